// Round 1
// baseline (110.485 us; speedup 1.0000x reference)
//
#include <hip/hip_runtime.h>

// Elementwise: out = sqrt((x + 5) * 2 - 3), fp32 in / fp32 out.
// Memory-bound: 512 MiB total traffic -> target ~6.3 TB/s achievable HBM BW.

__global__ void elemwise_sqrt_kernel(const float* __restrict__ in,
                                     float* __restrict__ out,
                                     int n4) {
    int idx = blockIdx.x * blockDim.x + threadIdx.x;
    int stride = gridDim.x * blockDim.x;
    const float4* in4 = reinterpret_cast<const float4*>(in);
    float4* out4 = reinterpret_cast<float4*>(out);
    for (int i = idx; i < n4; i += stride) {
        float4 v = in4[i];
        float4 r;
        r.x = sqrtf(fmaf(v.x, 2.0f, 7.0f));   // (x+5)*2-3 == 2x+7
        r.y = sqrtf(fmaf(v.y, 2.0f, 7.0f));
        r.z = sqrtf(fmaf(v.z, 2.0f, 7.0f));
        r.w = sqrtf(fmaf(v.w, 2.0f, 7.0f));
        out4[i] = r;
    }
}

extern "C" void kernel_launch(void* const* d_in, const int* in_sizes, int n_in,
                              void* d_out, int out_size, void* d_ws, size_t ws_size,
                              hipStream_t stream) {
    const float* in = (const float*)d_in[0];
    float* out = (float*)d_out;
    int n = in_sizes[0];          // 8192*8192 = 67108864, divisible by 4
    int n4 = n / 4;

    const int block = 256;
    int grid = (n4 + block - 1) / block;
    const int max_grid = 2048;    // 256 CUs x 8 blocks/CU; grid-stride the rest
    if (grid > max_grid) grid = max_grid;

    elemwise_sqrt_kernel<<<grid, block, 0, stream>>>(in, out, n4);
}